// Round 14
// baseline (83.644 us; speedup 1.0000x reference)
//
#include <hip/hip_runtime.h>
#include <math.h>

// Problem constants: gts/preds [4, 8192, 3] fp32; out [4] fp32.
#define BB 4
#define NPTS 8192
#define THREADS 256
#define NQ_TOTAL (2 * BB * NPTS)       // 65536 (dir,b,q) query slots
#define SLICES 4                       // ref-dim split; 32 KB LDS per block
#define RPS (NPTS / SLICES)            // 2048 refs per slice
#define QPW 64                         // queries per wave (TWO B fragments)
#define QPB_MIN (4 * QPW)              // 256 queries per block (4 waves)
#define QGROUPS (NPTS / QPB_MIN)       // 32 query groups per (dir,b)
#define NBLK_MIN (SLICES * 2 * BB * QGROUPS)   // 1024 blocks

typedef __attribute__((ext_vector_type(8)))  short bf16x8;   // MFMA A/B frag
typedef __attribute__((ext_vector_type(16))) float f32x16;   // MFMA C/D frag

// ws layout:
//   refpack: NQ_TOTAL uint4  bf16 [x,y,z,rr_hi,rr_lo,1,1,0]       1 MiB
//   qpack:   NQ_TOTAL uint4  bf16 [-2x,-2y,-2z,1,1,qq_hi,qq_lo,0] 1 MiB
//   minpart: SLICES * NQ_TOTAL float                              1 MiB
// MFMA dot = -2 q.r + rr + qq = |q-r|^2 on bf16-rounded points.
// Role-swapped (R13): A = refs (rows, LDS), B = queries (cols, persistent).
// B's K slots 8-15 zero -> A lanes 32-63 don't-care -> unconditional
// full-wave LDS reads. Each lane's D regs = 16 ref-rows for ITS query col
// -> min is register-local. R14: TWO B frags per wave so each ds_read pair
// feeds 4 MFMAs (LDS bytes per pair halved vs R13).

__device__ __forceinline__ unsigned short f2bf(float f) {   // RNE f32->bf16
    unsigned u = __float_as_uint(f);
    u += 0x7FFF + ((u >> 16) & 1);
    return (unsigned short)(u >> 16);
}
__device__ __forceinline__ float bf2f(unsigned short h) {
    return __uint_as_float(((unsigned)h) << 16);
}

// ---------------------------------------------------------------------------
// Kernel 1: round coords to bf16, build ref- and query-side fragments.
// rr/qq computed in fp32 FROM THE ROUNDED coords, fed as 2-term bf16 splits.
// ---------------------------------------------------------------------------
__global__ __launch_bounds__(THREADS) void pack_kernel(
    const float* __restrict__ gts, const float* __restrict__ preds,
    uint4* __restrict__ refpack, uint4* __restrict__ qpack,
    float* __restrict__ out) {
    int idx = blockIdx.x * THREADS + threadIdx.x;
    if (idx < BB) out[idx] = 0.0f;
    if (idx >= NQ_TOTAL) return;
    int set  = idx / (BB * NPTS);          // 0 = gts, 1 = preds
    int pidx = idx - set * (BB * NPTS);
    const float* src = set ? preds : gts;
    unsigned short hx = f2bf(src[pidx * 3 + 0]);
    unsigned short hy = f2bf(src[pidx * 3 + 1]);
    unsigned short hz = f2bf(src[pidx * 3 + 2]);
    float fx = bf2f(hx), fy = bf2f(hy), fz = bf2f(hz);
    float rr = fmaf(fx, fx, fmaf(fy, fy, fz * fz));
    unsigned short hrr = f2bf(rr);
    unsigned short hlo = f2bf(rr - bf2f(hrr));
    const unsigned short ONE = 0x3F80;      // 1.0 bf16

    uint4 rv;                               // ref slots: [x,y,z,rrhi,rrlo,1,1,0]
    rv.x = (unsigned)hx  | ((unsigned)hy  << 16);
    rv.y = (unsigned)hz  | ((unsigned)hrr << 16);
    rv.z = (unsigned)hlo | ((unsigned)ONE << 16);
    rv.w = (unsigned)ONE;
    refpack[idx] = rv;

    unsigned short nx = f2bf(-2.0f * fx);   // exact (coords already bf16)
    unsigned short ny = f2bf(-2.0f * fy);
    unsigned short nz = f2bf(-2.0f * fz);
    uint4 qv;                               // query slots: [-2x,-2y,-2z,1,1,qqhi,qqlo,0]
    qv.x = (unsigned)nx  | ((unsigned)ny  << 16);
    qv.y = (unsigned)nz  | ((unsigned)ONE << 16);
    qv.z = (unsigned)ONE | ((unsigned)hrr << 16);
    qv.w = (unsigned)hlo;
    qpack[idx] = qv;
}

// ---------------------------------------------------------------------------
// Kernel 2: MFMA min kernel, role-swapped + dual B-frag. Per iter: 2
// ds_read_b128 (64 refs) x 2 persistent query frags -> 4 MFMAs -> 4096
// pairs; 32 v_min3 into 4 register-local chains. Tail: 2 fminf + 2
// shfl_xor(32) + 2 coalesced 32-lane stores.
// D layout (m74/m101): col = lane&31, row = (r&3)+8*(r>>2)+4*(lane>>5).
// ---------------------------------------------------------------------------
__global__ __launch_bounds__(THREADS) void min_kernel(
    const uint4* __restrict__ refpack, const uint4* __restrict__ qpack,
    float* __restrict__ minpart) {
    __shared__ uint4 sref[RPS];            // 32 KB

    int tid   = threadIdx.x;
    int blk   = blockIdx.x;
    int slice = blk >> 8;                  // / (2*BB*QGROUPS) = /256
    int rem   = blk & 255;
    int dir   = rem >> 7;
    int b     = (rem >> 5) & 3;
    int qg    = rem & 31;                  // query group of 256
    int qset  = dir ^ 1;                   // dir0: queries=preds(set1), refs=gts
    int rset  = dir;

    // Stage the ref slice: 2048 uint4, 8 coalesced rounds of 256 lanes.
    const uint4* rgl = refpack + (size_t)(rset * BB + b) * NPTS
                     + (size_t)slice * RPS;
    #pragma unroll
    for (int i = 0; i < RPS / THREADS; ++i)
        sref[i * THREADS + tid] = rgl[i * THREADS + tid];
    __syncthreads();

    int wid  = tid >> 6;
    int lane = tid & 63;
    int l31  = lane & 31;

    // Two B fragments: lane l31 = query cols l31 / l31+32; lanes 32-63 zero.
    size_t qoff = (size_t)(qset * BB + b) * NPTS + (size_t)qg * QPB_MIN
                + (size_t)wid * QPW;
    bf16x8 bq0 = {0, 0, 0, 0, 0, 0, 0, 0};
    bf16x8 bq1 = {0, 0, 0, 0, 0, 0, 0, 0};
    if (lane < 32) {
        bq0 = ((const bf16x8*)qpack)[qoff + l31];
        bq1 = ((const bf16x8*)qpack)[qoff + 32 + l31];
    }

    f32x16 zeroc;
    #pragma unroll
    for (int r = 0; r < 16; ++r) zeroc[r] = 0.0f;

    float m00 = 3.0e38f, m01 = 3.0e38f, m10 = 3.0e38f, m11 = 3.0e38f;

    const bf16x8* sp = (const bf16x8*)sref;
    #pragma unroll 2
    for (int t = 0; t < RPS / 64; ++t) {   // 32 iters, 64 refs x 64 queries
        bf16x8 a0 = sp[t * 64 + l31];
        bf16x8 a1 = sp[t * 64 + 32 + l31];
        f32x16 d00 = __builtin_amdgcn_mfma_f32_32x32x16_bf16(a0, bq0, zeroc, 0, 0, 0);
        f32x16 d01 = __builtin_amdgcn_mfma_f32_32x32x16_bf16(a0, bq1, zeroc, 0, 0, 0);
        f32x16 d10 = __builtin_amdgcn_mfma_f32_32x32x16_bf16(a1, bq0, zeroc, 0, 0, 0);
        f32x16 d11 = __builtin_amdgcn_mfma_f32_32x32x16_bf16(a1, bq1, zeroc, 0, 0, 0);
        #pragma unroll
        for (int r = 0; r < 16; r += 2) {
            m00 = fminf(fminf(d00[r], d00[r + 1]), m00);   // v_min3_f32
            m01 = fminf(fminf(d01[r], d01[r + 1]), m01);
            m10 = fminf(fminf(d10[r], d10[r + 1]), m10);
            m11 = fminf(fminf(d11[r], d11[r + 1]), m11);
        }
    }

    // Query tile 0 saw refs a0 (m00) and a1 (m10); tile 1 likewise. The two
    // wave halves hold complementary ref-rows -> one shfl_xor(32) each.
    float q0 = fminf(m00, m10);
    float q1 = fminf(m01, m11);
    q0 = fminf(q0, __shfl_xor(q0, 32, 64));
    q1 = fminf(q1, __shfl_xor(q1, 32, 64));

    float* mp = minpart + (size_t)slice * NQ_TOTAL
              + (size_t)(dir * BB + b) * NPTS + (size_t)qg * QPB_MIN
              + (size_t)wid * QPW;
    if (lane < 32) {
        mp[l31]      = q0;
        mp[l31 + 32] = q1;
    }
}

// ---------------------------------------------------------------------------
// Kernel 3: merge slices, sqrt, block-reduce, atomicAdd into out[b].
// ---------------------------------------------------------------------------
__global__ __launch_bounds__(THREADS) void merge_kernel(
    const float* __restrict__ minpart, float* __restrict__ out) {
    int q = blockIdx.x * THREADS + threadIdx.x;    // 0 .. NQ_TOTAL-1
    float m = minpart[q];
    #pragma unroll
    for (int s = 1; s < SLICES; ++s)
        m = fminf(m, minpart[(size_t)s * NQ_TOTAL + q]);
    float d = sqrtf(fmaxf(m, 0.0f));
    int b = (q >> 13) & 3;                         // uniform within a block

    float sum = d;
    #pragma unroll
    for (int off = 32; off > 0; off >>= 1)
        sum += __shfl_down(sum, off, 64);

    __shared__ float wsum[THREADS / 64];
    int lane = threadIdx.x & 63;
    int wid  = threadIdx.x >> 6;
    if (lane == 0) wsum[wid] = sum;
    __syncthreads();
    if (threadIdx.x == 0)
        atomicAdd(out + b, wsum[0] + wsum[1] + wsum[2] + wsum[3]);
}

extern "C" void kernel_launch(void* const* d_in, const int* in_sizes, int n_in,
                              void* d_out, int out_size, void* d_ws, size_t ws_size,
                              hipStream_t stream) {
    const float* gts   = (const float*)d_in[0];
    const float* preds = (const float*)d_in[1];
    float* out = (float*)d_out;

    char* ws = (char*)d_ws;
    uint4* refpack = (uint4*)ws;                                   // 1 MiB
    uint4* qpack   = (uint4*)(ws + (size_t)NQ_TOTAL * 16);         // 1 MiB
    float* minpart = (float*)(ws + (size_t)NQ_TOTAL * 32);         // 1 MiB

    pack_kernel<<<NQ_TOTAL / THREADS, THREADS, 0, stream>>>(
        gts, preds, refpack, qpack, out);

    min_kernel<<<NBLK_MIN, THREADS, 0, stream>>>(refpack, qpack, minpart);

    merge_kernel<<<NQ_TOTAL / THREADS, THREADS, 0, stream>>>(minpart, out);
}

// Round 15
// 82.826 us; speedup vs baseline: 1.0099x; 1.0099x over previous
//
#include <hip/hip_runtime.h>
#include <math.h>

// Problem constants: gts/preds [4, 8192, 3] fp32; out [4] fp32.
#define BB 4
#define NPTS 8192
#define THREADS 256
#define NQ_TOTAL (2 * BB * NPTS)       // 65536 (dir,b,q) query slots
#define SLICES 4                       // ref-dim split; 32 KB LDS per block
#define RPS (NPTS / SLICES)            // 2048 refs per slice
#define QPW 32                         // queries per wave (one B fragment)
#define QPB_MIN (4 * QPW)              // 128 queries per block (4 waves)
#define QGROUPS (NPTS / QPB_MIN)       // 64 query groups per (dir,b)
#define NBLK_MIN (SLICES * 2 * BB * QGROUPS)   // 2048 blocks

typedef __attribute__((ext_vector_type(8)))  short bf16x8;   // MFMA A/B frag
typedef __attribute__((ext_vector_type(16))) float f32x16;   // MFMA C/D frag

// ws layout:
//   refpack: NQ_TOTAL uint4  bf16 [x,y,z,rr_hi,rr_lo,1,1,0]       1 MiB
//   qpack:   NQ_TOTAL uint4  bf16 [-2x,-2y,-2z,1,1,qq_hi,qq_lo,0] 1 MiB
//   minpart: SLICES * NQ_TOTAL float                              1 MiB
// MFMA dot = -2 q.r + rr + qq = |q-r|^2 on bf16-rounded points.
// Role-swapped (R13): A = refs (rows, LDS), B = queries (cols, persistent).
// R15: explicit SW pipeline — MFMAs for tile t+1 issue BEFORE folding tile
// t's results (min3s independent of in-flight MFMAs), 4 independent acc
// chains (dep depth 4/iter instead of 8).

__device__ __forceinline__ unsigned short f2bf(float f) {   // RNE f32->bf16
    unsigned u = __float_as_uint(f);
    u += 0x7FFF + ((u >> 16) & 1);
    return (unsigned short)(u >> 16);
}
__device__ __forceinline__ float bf2f(unsigned short h) {
    return __uint_as_float(((unsigned)h) << 16);
}

// ---------------------------------------------------------------------------
// Kernel 1: round coords to bf16, build ref- and query-side fragments.
// rr/qq computed in fp32 FROM THE ROUNDED coords, fed as 2-term bf16 splits.
// ---------------------------------------------------------------------------
__global__ __launch_bounds__(THREADS) void pack_kernel(
    const float* __restrict__ gts, const float* __restrict__ preds,
    uint4* __restrict__ refpack, uint4* __restrict__ qpack,
    float* __restrict__ out) {
    int idx = blockIdx.x * THREADS + threadIdx.x;
    if (idx < BB) out[idx] = 0.0f;
    if (idx >= NQ_TOTAL) return;
    int set  = idx / (BB * NPTS);          // 0 = gts, 1 = preds
    int pidx = idx - set * (BB * NPTS);
    const float* src = set ? preds : gts;
    unsigned short hx = f2bf(src[pidx * 3 + 0]);
    unsigned short hy = f2bf(src[pidx * 3 + 1]);
    unsigned short hz = f2bf(src[pidx * 3 + 2]);
    float fx = bf2f(hx), fy = bf2f(hy), fz = bf2f(hz);
    float rr = fmaf(fx, fx, fmaf(fy, fy, fz * fz));
    unsigned short hrr = f2bf(rr);
    unsigned short hlo = f2bf(rr - bf2f(hrr));
    const unsigned short ONE = 0x3F80;      // 1.0 bf16

    uint4 rv;                               // ref slots: [x,y,z,rrhi,rrlo,1,1,0]
    rv.x = (unsigned)hx  | ((unsigned)hy  << 16);
    rv.y = (unsigned)hz  | ((unsigned)hrr << 16);
    rv.z = (unsigned)hlo | ((unsigned)ONE << 16);
    rv.w = (unsigned)ONE;
    refpack[idx] = rv;

    unsigned short nx = f2bf(-2.0f * fx);   // exact (coords already bf16)
    unsigned short ny = f2bf(-2.0f * fy);
    unsigned short nz = f2bf(-2.0f * fz);
    uint4 qv;                               // query slots: [-2x,-2y,-2z,1,1,qqhi,qqlo,0]
    qv.x = (unsigned)nx  | ((unsigned)ny  << 16);
    qv.y = (unsigned)nz  | ((unsigned)ONE << 16);
    qv.z = (unsigned)ONE | ((unsigned)hrr << 16);
    qv.w = (unsigned)hlo;
    qpack[idx] = qv;
}

// ---------------------------------------------------------------------------
// Kernel 2: MFMA min kernel, role-swapped + explicit SW pipeline.
// Per steady-state iter: 2 ds_read_b128 + 2 MFMA issued for tile t, THEN 16
// v_min3 folding tile t-1's (already-landed) results into 4 independent
// chains. Tail: 3 fminf + 1 shfl_xor(32) + coalesced 32-lane store.
// D layout (m74/m101): col = lane&31, row = (r&3)+8*(r>>2)+4*(lane>>5).
// ---------------------------------------------------------------------------
__global__ __launch_bounds__(THREADS) void min_kernel(
    const uint4* __restrict__ refpack, const uint4* __restrict__ qpack,
    float* __restrict__ minpart) {
    __shared__ uint4 sref[RPS];            // 32 KB

    int tid   = threadIdx.x;
    int blk   = blockIdx.x;
    int slice = blk >> 9;                  // / (2*BB*QGROUPS) = /512
    int rem   = blk & 511;
    int dir   = rem >> 8;
    int b     = (rem >> 6) & 3;
    int qg    = rem & 63;                  // query group of 128
    int qset  = dir ^ 1;                   // dir0: queries=preds(set1), refs=gts
    int rset  = dir;

    // Stage the ref slice: 2048 uint4, 8 coalesced rounds of 256 lanes.
    const uint4* rgl = refpack + (size_t)(rset * BB + b) * NPTS
                     + (size_t)slice * RPS;
    #pragma unroll
    for (int i = 0; i < RPS / THREADS; ++i)
        sref[i * THREADS + tid] = rgl[i * THREADS + tid];
    __syncthreads();

    int wid  = tid >> 6;
    int lane = tid & 63;
    int l31  = lane & 31;

    // B fragment: lane l31 = query col l31 (K slots 0-7); lanes 32-63 zero.
    size_t qoff = (size_t)(qset * BB + b) * NPTS + (size_t)qg * QPB_MIN
                + (size_t)wid * QPW;
    bf16x8 bq = {0, 0, 0, 0, 0, 0, 0, 0};
    if (lane < 32) bq = ((const bf16x8*)qpack)[qoff + l31];

    f32x16 zeroc;
    #pragma unroll
    for (int r = 0; r < 16; ++r) zeroc[r] = 0.0f;

    float c0 = 3.0e38f, c1 = 3.0e38f, c2 = 3.0e38f, c3 = 3.0e38f;

    const bf16x8* sp = (const bf16x8*)sref;

    // Prologue: tile 0 in flight.
    f32x16 p0 = __builtin_amdgcn_mfma_f32_32x32x16_bf16(sp[l31], bq, zeroc, 0, 0, 0);
    f32x16 p1 = __builtin_amdgcn_mfma_f32_32x32x16_bf16(sp[32 + l31], bq, zeroc, 0, 0, 0);

    #pragma unroll 2
    for (int t = 1; t < RPS / 64; ++t) {
        // Issue tile t's loads + MFMAs first (independent of the folds below).
        bf16x8 n0 = sp[t * 64 + l31];
        bf16x8 n1 = sp[t * 64 + 32 + l31];
        f32x16 d0 = __builtin_amdgcn_mfma_f32_32x32x16_bf16(n0, bq, zeroc, 0, 0, 0);
        f32x16 d1 = __builtin_amdgcn_mfma_f32_32x32x16_bf16(n1, bq, zeroc, 0, 0, 0);
        // Fold tile t-1 (landed long ago): 4 independent min3 chains.
        #pragma unroll
        for (int r = 0; r < 16; r += 4) {
            c0 = fminf(fminf(p0[r],     p0[r + 1]), c0);   // v_min3_f32
            c1 = fminf(fminf(p0[r + 2], p0[r + 3]), c1);
            c2 = fminf(fminf(p1[r],     p1[r + 1]), c2);
            c3 = fminf(fminf(p1[r + 2], p1[r + 3]), c3);
        }
        p0 = d0;                            // renamed away under unroll
        p1 = d1;
    }
    // Epilogue: fold the last tile.
    #pragma unroll
    for (int r = 0; r < 16; r += 4) {
        c0 = fminf(fminf(p0[r],     p0[r + 1]), c0);
        c1 = fminf(fminf(p0[r + 2], p0[r + 3]), c1);
        c2 = fminf(fminf(p1[r],     p1[r + 1]), c2);
        c3 = fminf(fminf(p1[r + 2], p1[r + 3]), c3);
    }

    // Combine chains; halves hold complementary ref-rows -> one shfl_xor.
    float m = fminf(fminf(c0, c1), fminf(c2, c3));
    m = fminf(m, __shfl_xor(m, 32, 64));

    float* mp = minpart + (size_t)slice * NQ_TOTAL
              + (size_t)(dir * BB + b) * NPTS + (size_t)qg * QPB_MIN
              + (size_t)wid * QPW;
    if (lane < 32) mp[l31] = m;
}

// ---------------------------------------------------------------------------
// Kernel 3: merge slices, sqrt, block-reduce, atomicAdd into out[b].
// ---------------------------------------------------------------------------
__global__ __launch_bounds__(THREADS) void merge_kernel(
    const float* __restrict__ minpart, float* __restrict__ out) {
    int q = blockIdx.x * THREADS + threadIdx.x;    // 0 .. NQ_TOTAL-1
    float m = minpart[q];
    #pragma unroll
    for (int s = 1; s < SLICES; ++s)
        m = fminf(m, minpart[(size_t)s * NQ_TOTAL + q]);
    float d = sqrtf(fmaxf(m, 0.0f));
    int b = (q >> 13) & 3;                         // uniform within a block

    float sum = d;
    #pragma unroll
    for (int off = 32; off > 0; off >>= 1)
        sum += __shfl_down(sum, off, 64);

    __shared__ float wsum[THREADS / 64];
    int lane = threadIdx.x & 63;
    int wid  = threadIdx.x >> 6;
    if (lane == 0) wsum[wid] = sum;
    __syncthreads();
    if (threadIdx.x == 0)
        atomicAdd(out + b, wsum[0] + wsum[1] + wsum[2] + wsum[3]);
}

extern "C" void kernel_launch(void* const* d_in, const int* in_sizes, int n_in,
                              void* d_out, int out_size, void* d_ws, size_t ws_size,
                              hipStream_t stream) {
    const float* gts   = (const float*)d_in[0];
    const float* preds = (const float*)d_in[1];
    float* out = (float*)d_out;

    char* ws = (char*)d_ws;
    uint4* refpack = (uint4*)ws;                                   // 1 MiB
    uint4* qpack   = (uint4*)(ws + (size_t)NQ_TOTAL * 16);         // 1 MiB
    float* minpart = (float*)(ws + (size_t)NQ_TOTAL * 32);         // 1 MiB

    pack_kernel<<<NQ_TOTAL / THREADS, THREADS, 0, stream>>>(
        gts, preds, refpack, qpack, out);

    min_kernel<<<NBLK_MIN, THREADS, 0, stream>>>(refpack, qpack, minpart);

    merge_kernel<<<NQ_TOTAL / THREADS, THREADS, 0, stream>>>(minpart, out);
}